// Round 1
// baseline (197.434 us; speedup 1.0000x reference)
//
#include <hip/hip_runtime.h>

// out[i] = sin(a_i) * sin(b_i); input: 16.7M interleaved (a,b) fp32 pairs.
// Memory-bound streaming: 128 MiB read + 64 MiB write = 201.3 MB/call.
// Floor ~31 us at 6.3 TB/s mixed-stream ceiling. dur_us also contains
// ~157 us of harness poison fills (2x 512 MiB @ ~78 us, seen in rocprof),
// so total floor ~188-190 us.
//
// v2 changes vs 194.0 us baseline:
//  - 16B vfloat4 stores (was 2x 8B vfloat2): halves store instruction count.
//    Thread owns 4 consecutive outputs -> needs 32B/lane input = 2 dwordx4
//    loads at lane-stride 32B (pair fully covers every line back-to-back).
//  - x2 unroll: 4 global_load_dwordx4 in flight per wave before first store
//    (more MLP at same occupancy, ~28 VGPR).
// Zero reuse -> nontemporal loads/stores (skip L2/L3 retention; the harness
// poison fill thrashes L3 anyway).
typedef float vfloat4 __attribute__((ext_vector_type(4)));

__global__ __launch_bounds__(256) void sinprod_kernel(
    const vfloat4* __restrict__ in, vfloat4* __restrict__ out, int nOut4) {
    // t = output float4 index; covers out floats [4t,4t+4) from in f4 {2t,2t+1}
    int t0 = blockIdx.x * (blockDim.x * 2) + threadIdx.x;
    int t1 = t0 + blockDim.x;
    if (t1 < nOut4) {
        vfloat4 a0 = __builtin_nontemporal_load(&in[2 * t0]);
        vfloat4 a1 = __builtin_nontemporal_load(&in[2 * t0 + 1]);
        vfloat4 b0 = __builtin_nontemporal_load(&in[2 * t1]);
        vfloat4 b1 = __builtin_nontemporal_load(&in[2 * t1 + 1]);
        vfloat4 oa, ob;
        oa.x = __sinf(a0.x) * __sinf(a0.y);
        oa.y = __sinf(a0.z) * __sinf(a0.w);
        oa.z = __sinf(a1.x) * __sinf(a1.y);
        oa.w = __sinf(a1.z) * __sinf(a1.w);
        ob.x = __sinf(b0.x) * __sinf(b0.y);
        ob.y = __sinf(b0.z) * __sinf(b0.w);
        ob.z = __sinf(b1.x) * __sinf(b1.y);
        ob.w = __sinf(b1.z) * __sinf(b1.w);
        __builtin_nontemporal_store(oa, &out[t0]);
        __builtin_nontemporal_store(ob, &out[t1]);
    }
}

extern "C" void kernel_launch(void* const* d_in, const int* in_sizes, int n_in,
                              void* d_out, int out_size, void* d_ws, size_t ws_size,
                              hipStream_t stream) {
    const vfloat4* in = (const vfloat4*)d_in[0];
    vfloat4* out = (vfloat4*)d_out;
    int nOut4 = out_size / 4;        // 4,194,304 float4 outputs
    int block = 256;
    int grid = nOut4 / (block * 2);  // 8192 blocks, exact (nOut4 % 512 == 0)
    sinprod_kernel<<<grid, block, 0, stream>>>(in, out, nOut4);
}

// Round 2
// 196.792 us; speedup vs baseline: 1.0033x; 1.0033x over previous
//
#include <hip/hip_runtime.h>

// out[i] = sin(a_i) * sin(b_i); input: 16.7M interleaved (a,b) fp32 pairs.
// Memory-bound streaming: 128 MiB read + 64 MiB write = 201.3 MB/call.
// Kernel floor ~32 us at 6.29 TB/s mixed-stream ceiling (m13). dur_us also
// contains ~157-159 us of harness poison fills (2x 512 MiB @ ~78-80 us,
// visible in rocprof top-5), so total floor ~189-191 us.
//
// v3 (after v2 post-mortem): v2's lane-stride-32B loads regressed (-3.4us):
// per-instruction line density 50% doubles TA/TCP requests. Lesson: lane
// stride MUST equal access width for streams. Store width is irrelevant
// (BW-bound, 512B/wave/instr either way).
//   - contiguous lane-stride-16B dwordx4 loads (baseline pattern, proven)
//   - x4 unroll: 4 independent loads issued back-to-back before the
//     dependent sin->store chains (2x the MLP of the 194.0us baseline)
//   - vfloat2 stores, contiguous lane-stride-8B
// Zero reuse -> nontemporal loads/stores.
typedef float vfloat4 __attribute__((ext_vector_type(4)));
typedef float vfloat2 __attribute__((ext_vector_type(2)));

__global__ __launch_bounds__(256) void sinprod_kernel(
    const vfloat4* __restrict__ in, vfloat2* __restrict__ out, int n4) {
    int base = blockIdx.x * (blockDim.x * 4) + threadIdx.x;
    int i0 = base;
    int i1 = base + blockDim.x;
    int i2 = base + 2 * blockDim.x;
    int i3 = base + 3 * blockDim.x;
    if (i3 < n4) {
        vfloat4 v0 = __builtin_nontemporal_load(&in[i0]);
        vfloat4 v1 = __builtin_nontemporal_load(&in[i1]);
        vfloat4 v2 = __builtin_nontemporal_load(&in[i2]);
        vfloat4 v3 = __builtin_nontemporal_load(&in[i3]);
        vfloat2 o0, o1, o2, o3;
        o0.x = __sinf(v0.x) * __sinf(v0.y);
        o0.y = __sinf(v0.z) * __sinf(v0.w);
        o1.x = __sinf(v1.x) * __sinf(v1.y);
        o1.y = __sinf(v1.z) * __sinf(v1.w);
        o2.x = __sinf(v2.x) * __sinf(v2.y);
        o2.y = __sinf(v2.z) * __sinf(v2.w);
        o3.x = __sinf(v3.x) * __sinf(v3.y);
        o3.y = __sinf(v3.z) * __sinf(v3.w);
        __builtin_nontemporal_store(o0, &out[i0]);
        __builtin_nontemporal_store(o1, &out[i1]);
        __builtin_nontemporal_store(o2, &out[i2]);
        __builtin_nontemporal_store(o3, &out[i3]);
    }
}

extern "C" void kernel_launch(void* const* d_in, const int* in_sizes, int n_in,
                              void* d_out, int out_size, void* d_ws, size_t ws_size,
                              hipStream_t stream) {
    const vfloat4* in = (const vfloat4*)d_in[0];
    vfloat2* out = (vfloat2*)d_out;
    int n4 = out_size / 2;           // 8,388,608 float4-input rows
    int block = 256;
    int grid = n4 / (block * 4);     // 8192 blocks, exact (n4 % 1024 == 0)
    sinprod_kernel<<<grid, block, 0, stream>>>(in, out, n4);
}

// Round 3
// 195.434 us; speedup vs baseline: 1.0102x; 1.0070x over previous
//
#include <hip/hip_runtime.h>

// out[i] = sin(a_i) * sin(b_i), input interleaved (a,b) pairs, fp32.
// Memory-bound streaming: 128 MiB read + 64 MiB write per call.
// dur_us also contains ~157-159 us of harness poison fills (2x 512 MiB
// @ ~78-80 us each, visible in rocprof top-5); kernel portion ~37 us
// = 5.4 TB/s effective on the 2:1 read:write mix (copy ceiling 6.29 TB/s).
//
// MEASURED LADDER (do not re-try):
//   v1 (this): stride-16B loads, x2 unroll, vfloat2 stores   -> 194.0 us BEST
//   v2: lane-stride-32B load pairs + vfloat4 stores          -> 197.4 us
//       (50% per-instruction line density doubles TA/TCP requests)
//   v3: x4 unroll (4 loads in flight)                        -> 196.8 us
//       (MLP beyond 2 buys nothing; BW-floor, not latency-bound)
// Lesson: for pure streams, lane stride == access width is the only
// pattern that matters; store width and extra MLP are irrelevant.
// Zero reuse -> nontemporal loads/stores (skip L2/L3 retention).
typedef float vfloat4 __attribute__((ext_vector_type(4)));
typedef float vfloat2 __attribute__((ext_vector_type(2)));

__global__ __launch_bounds__(256) void sinprod_kernel(
    const vfloat4* __restrict__ in, vfloat2* __restrict__ out, int n4) {
    int i0 = blockIdx.x * (blockDim.x * 2) + threadIdx.x;
    int i1 = i0 + blockDim.x;
    if (i1 < n4) {
        vfloat4 v0 = __builtin_nontemporal_load(&in[i0]);
        vfloat4 v1 = __builtin_nontemporal_load(&in[i1]);
        vfloat2 o0, o1;
        o0.x = __sinf(v0.x) * __sinf(v0.y);
        o0.y = __sinf(v0.z) * __sinf(v0.w);
        o1.x = __sinf(v1.x) * __sinf(v1.y);
        o1.y = __sinf(v1.z) * __sinf(v1.w);
        __builtin_nontemporal_store(o0, &out[i0]);
        __builtin_nontemporal_store(o1, &out[i1]);
    }
}

extern "C" void kernel_launch(void* const* d_in, const int* in_sizes, int n_in,
                              void* d_out, int out_size, void* d_ws, size_t ws_size,
                              hipStream_t stream) {
    const vfloat4* in = (const vfloat4*)d_in[0];
    vfloat2* out = (vfloat2*)d_out;
    int n4 = out_size / 2;          // 8,388,608 float4 rows-pairs
    int block = 256;
    int grid = n4 / (block * 2);    // 16384 blocks, exact (n4 % 512 == 0)
    sinprod_kernel<<<grid, block, 0, stream>>>(in, out, n4);
}